// Round 1
// baseline (2116.057 us; speedup 1.0000x reference)
//
#include <hip/hip_runtime.h>

#define NN 50000
#define NE 800000
#define FIN 256
#define C 64
#define NEG_SLOPE 0.01f

__device__ __forceinline__ float leaky(float v) { return v > 0.f ? v : NEG_SLOPE * v; }

// ---------------------------------------------------------------------------
// K0: h = leaky_relu(x @ Wf + bf)   x:[N,256] Wf:[256,64]
// Block = 256 thr (4 waves). Wf staged in 64KB LDS. One wave per node row,
// lane c owns output channel c; x row read as broadcast float4.
// ---------------------------------------------------------------------------
#define K0_NODES 32
__global__ __launch_bounds__(256) void k_feat(const float* __restrict__ x,
                                              const float* __restrict__ Wf,
                                              const float* __restrict__ bf,
                                              float* __restrict__ h) {
    __shared__ float WL[FIN * C];  // 64 KB
    const float4* Wf4 = (const float4*)Wf;
    float4* WL4 = (float4*)WL;
    for (int i = threadIdx.x; i < FIN * C / 4; i += 256) WL4[i] = Wf4[i];
    __syncthreads();
    const int wave = threadIdx.x >> 6;
    const int lane = threadIdx.x & 63;
    const float bias = bf[lane];
    const int base = blockIdx.x * K0_NODES;
    for (int n = base + wave; n < base + K0_NODES && n < NN; n += 4) {
        const float4* xr = (const float4*)(x + (size_t)n * FIN);
        float sum = 0.f;
#pragma unroll 8
        for (int k4 = 0; k4 < FIN / 4; ++k4) {
            float4 xv = xr[k4];
            const float* w = &WL[k4 * 4 * C + lane];
            sum += xv.x * w[0] + xv.y * w[C] + xv.z * w[2 * C] + xv.w * w[3 * C];
        }
        h[n * C + lane] = leaky(sum + bias);
    }
}

// ---------------------------------------------------------------------------
// K1: qkvs[n, m*64+c] = h[n,:] @ W_m + b_m   for m in {q,k,v,skip}
// All four 64x64 weight mats staged in LDS as [k][m*64+c] (64KB).
// ---------------------------------------------------------------------------
#define K1_NODES 32
__global__ __launch_bounds__(256) void k_qkvs(const float* __restrict__ h,
                                              const float* __restrict__ Wq, const float* __restrict__ bq,
                                              const float* __restrict__ Wk, const float* __restrict__ bk,
                                              const float* __restrict__ Wv, const float* __restrict__ bv,
                                              const float* __restrict__ Ws, const float* __restrict__ bs,
                                              float* __restrict__ qkvs) {
    __shared__ float WL[C * 4 * C];  // [k][m*64+c], 64 KB
    for (int i = threadIdx.x; i < C * C; i += 256) {
        int k = i >> 6, c = i & 63;
        WL[k * 256 + 0 + c]   = Wq[i];
        WL[k * 256 + 64 + c]  = Wk[i];
        WL[k * 256 + 128 + c] = Wv[i];
        WL[k * 256 + 192 + c] = Ws[i];
    }
    __syncthreads();
    const int wave = threadIdx.x >> 6;
    const int lane = threadIdx.x & 63;
    const float b0 = bq[lane], b1 = bk[lane], b2 = bv[lane], b3 = bs[lane];
    const int base = blockIdx.x * K1_NODES;
    for (int n = base + wave; n < base + K1_NODES && n < NN; n += 4) {
        const float4* hr = (const float4*)(h + n * C);
        float s0 = 0.f, s1 = 0.f, s2 = 0.f, s3 = 0.f;
#pragma unroll
        for (int k4 = 0; k4 < C / 4; ++k4) {
            float4 hv = hr[k4];
            const float* w = &WL[k4 * 4 * 256 + lane];
            s0 += hv.x * w[0]       + hv.y * w[256]       + hv.z * w[512]       + hv.w * w[768];
            s1 += hv.x * w[64]      + hv.y * w[256 + 64]  + hv.z * w[512 + 64]  + hv.w * w[768 + 64];
            s2 += hv.x * w[128]     + hv.y * w[256 + 128] + hv.z * w[512 + 128] + hv.w * w[768 + 128];
            s3 += hv.x * w[192]     + hv.y * w[256 + 192] + hv.z * w[512 + 192] + hv.w * w[768 + 192];
        }
        float* o = qkvs + (size_t)n * 256;
        o[lane]       = s0 + b0;
        o[64 + lane]  = s1 + b1;
        o[128 + lane] = s2 + b2;
        o[192 + lane] = s3 + b3;  // skip path: bias included here
    }
}

// ---------------------------------------------------------------------------
// K2: per-edge attention logit + segment max. One wave per edge.
// alpha = dot(q[dst], k[src] + e) / 8 ; e recomputed from edge_attr.
// Ordered-uint encoding for float atomicMax (init 0 < encode(-inf)).
// ---------------------------------------------------------------------------
__global__ __launch_bounds__(256) void k_alpha(const int* __restrict__ ei,
                                               const float* __restrict__ eattr,
                                               const float* __restrict__ We,
                                               const float* __restrict__ qkvs,
                                               float* __restrict__ alpha,
                                               unsigned int* __restrict__ menc) {
    const int wid = (blockIdx.x * 256 + threadIdx.x) >> 6;
    const int lane = threadIdx.x & 63;
    if (wid >= NE) return;
    const int src = ei[wid];
    const int dst = ei[NE + wid];
    const float ea0 = eattr[wid * 2], ea1 = eattr[wid * 2 + 1];
    const float ec = ea0 * We[lane] + ea1 * We[C + lane];
    const float qd = qkvs[(size_t)dst * 256 + lane];
    const float ks = qkvs[(size_t)src * 256 + 64 + lane];
    float p = qd * (ks + ec);
#pragma unroll
    for (int off = 32; off > 0; off >>= 1) p += __shfl_xor(p, off, 64);
    if (lane == 0) {
        const float a = p * 0.125f;  // 1/sqrt(64)
        alpha[wid] = a;
        const unsigned int b = __float_as_uint(a);
        const unsigned int e = (b & 0x80000000u) ? ~b : (b | 0x80000000u);
        atomicMax(&menc[dst], e);
    }
}

// ---------------------------------------------------------------------------
// K3: ex = exp(alpha - m[dst]); den[dst] += ex. One thread per edge.
// ---------------------------------------------------------------------------
__global__ __launch_bounds__(256) void k_exp(const int* __restrict__ ei,
                                             const unsigned int* __restrict__ menc,
                                             float* __restrict__ alpha,
                                             float* __restrict__ den) {
    const int e = blockIdx.x * 256 + threadIdx.x;
    if (e >= NE) return;
    const int dst = ei[NE + e];
    const unsigned int u = menc[dst];
    const unsigned int b = (u & 0x80000000u) ? (u & 0x7FFFFFFFu) : ~u;
    const float m = __uint_as_float(b);
    const float ex = __expf(alpha[e] - m);
    alpha[e] = ex;
    atomicAdd(&den[dst], ex);
}

// ---------------------------------------------------------------------------
// K4: agg[dst] += (v[src] + e) * (ex/den[dst]). One wave per edge; lane c
// issues one atomicAdd to consecutive addresses (cacheline-coalesced).
// ---------------------------------------------------------------------------
__global__ __launch_bounds__(256) void k_scatter(const int* __restrict__ ei,
                                                 const float* __restrict__ eattr,
                                                 const float* __restrict__ We,
                                                 const float* __restrict__ qkvs,
                                                 const float* __restrict__ alpha,
                                                 const float* __restrict__ den,
                                                 float* __restrict__ agg) {
    const int wid = (blockIdx.x * 256 + threadIdx.x) >> 6;
    const int lane = threadIdx.x & 63;
    if (wid >= NE) return;
    const int src = ei[wid];
    const int dst = ei[NE + wid];
    const float a = alpha[wid] / den[dst];
    const float ea0 = eattr[wid * 2], ea1 = eattr[wid * 2 + 1];
    const float ec = ea0 * We[lane] + ea1 * We[C + lane];
    const float v = qkvs[(size_t)src * 256 + 128 + lane];
    atomicAdd(&agg[dst * C + lane], (v + ec) * a);
}

// ---------------------------------------------------------------------------
// K5: h_out = leaky_relu(agg + (h@Wskip + bskip))   (skip already in qkvs slot 3)
// ---------------------------------------------------------------------------
__global__ __launch_bounds__(256) void k_update(const float* __restrict__ agg,
                                                const float* __restrict__ qkvs,
                                                float* __restrict__ hout) {
    const int idx = blockIdx.x * 256 + threadIdx.x;
    if (idx >= NN * C) return;
    const int n = idx >> 6, c = idx & 63;
    hout[idx] = leaky(agg[idx] + qkvs[(size_t)n * 256 + 192 + c]);
}

extern "C" void kernel_launch(void* const* d_in, const int* in_sizes, int n_in,
                              void* d_out, int out_size, void* d_ws, size_t ws_size,
                              hipStream_t stream) {
    const float* x     = (const float*)d_in[0];
    const int*   ei    = (const int*)d_in[1];
    const float* eattr = (const float*)d_in[2];
    const float* Wf    = (const float*)d_in[3];
    const float* bf    = (const float*)d_in[4];
    const float* Wq    = (const float*)d_in[5];
    const float* bq    = (const float*)d_in[6];
    const float* Wk    = (const float*)d_in[7];
    const float* bk    = (const float*)d_in[8];
    const float* Wv    = (const float*)d_in[9];
    const float* bv    = (const float*)d_in[10];
    const float* We    = (const float*)d_in[11];
    const float* Ws    = (const float*)d_in[12];
    const float* bs    = (const float*)d_in[13];
    float* out = (float*)d_out;

    // workspace layout (menc/den/agg contiguous for single memset)
    char* p = (char*)d_ws;
    float* h     = (float*)p; p += (size_t)NN * C * 4;       // 12.8 MB
    float* qkvs  = (float*)p; p += (size_t)NN * 4 * C * 4;   // 51.2 MB
    float* alpha = (float*)p; p += (size_t)NE * 4;           //  3.2 MB
    unsigned int* menc = (unsigned int*)p; p += (size_t)NN * 4;
    float* den   = (float*)p; p += (size_t)NN * 4;
    float* agg   = (float*)p; p += (size_t)NN * C * 4;       // 12.8 MB
    const size_t zero_bytes = ((size_t)NN + NN + (size_t)NN * C) * 4;

    k_feat<<<(NN + K0_NODES - 1) / K0_NODES, 256, 0, stream>>>(x, Wf, bf, h);

    for (int layer = 0; layer < 3; ++layer) {
        k_qkvs<<<(NN + K1_NODES - 1) / K1_NODES, 256, 0, stream>>>(
            h, Wq, bq, Wk, bk, Wv, bv, Ws, bs, qkvs);
        hipMemsetAsync(menc, 0, zero_bytes, stream);
        k_alpha<<<NE / 4, 256, 0, stream>>>(ei, eattr, We, qkvs, alpha, menc);
        k_exp<<<NE / 256, 256, 0, stream>>>(ei, menc, alpha, den);
        k_scatter<<<NE / 4, 256, 0, stream>>>(ei, eattr, We, qkvs, alpha, den, agg);
        float* hout = (layer == 2) ? out : h;
        k_update<<<(NN * C + 255) / 256, 256, 0, stream>>>(agg, qkvs, hout);
    }
}

// Round 2
// 1418.894 us; speedup vs baseline: 1.4913x; 1.4913x over previous
//
#include <hip/hip_runtime.h>

#define NN 50000
#define NE 800000
#define FIN 256
#define C 64
#define NEG_SLOPE 0.01f

__device__ __forceinline__ float leaky(float v) { return v > 0.f ? v : NEG_SLOPE * v; }

// ---------------------------------------------------------------------------
// K0: h = leaky_relu(x @ Wf + bf)   x:[N,256] Wf:[256,64]
// Tile = 32 nodes. Thread (c = t&63, g = t>>6); group g owns 8 nodes.
// k chunked by 32: x chunk staged in LDS (4KB), weight chunk w[32] in regs.
// LDS reads are wave-uniform (broadcast, conflict-free).
// ---------------------------------------------------------------------------
__global__ __launch_bounds__(256) void k_feat(const float* __restrict__ x,
                                              const float* __restrict__ Wf,
                                              const float* __restrict__ bf,
                                              float* __restrict__ h) {
    __shared__ float xs[32][32];
    const int t = threadIdx.x;
    const int c = t & 63;
    const int g = t >> 6;
    const int base = blockIdx.x * 32;
    float acc[8];
#pragma unroll
    for (int i = 0; i < 8; ++i) acc[i] = 0.f;

    for (int kc = 0; kc < 8; ++kc) {
        __syncthreads();
        {   // stage x[base..base+31][kc*32 .. +32): 256 float4, 1 per thread
            const int row = t >> 3, f4 = t & 7;
            int n = base + row; if (n >= NN) n = NN - 1;
            *(float4*)&xs[row][f4 * 4] =
                *(const float4*)(x + (size_t)n * FIN + kc * 32 + f4 * 4);
        }
        __syncthreads();
        float w[32];
#pragma unroll
        for (int j = 0; j < 32; ++j) w[j] = Wf[(kc * 32 + j) * C + c];
#pragma unroll
        for (int i = 0; i < 8; ++i) {
            const float* xr = &xs[g * 8 + i][0];
#pragma unroll
            for (int j = 0; j < 32; ++j) acc[i] += xr[j] * w[j];
        }
    }
    const float bias = bf[c];
#pragma unroll
    for (int i = 0; i < 8; ++i) {
        const int n = base + g * 8 + i;
        if (n < NN) h[(size_t)n * C + c] = leaky(acc[i] + bias);
    }
}

// ---------------------------------------------------------------------------
// K1: qkvs[n, m*64+c] = h[n,:] @ W_m + b_m   for m in {q,k,v,skip}
// Tile = 32 nodes; wave m owns matrix m (wave-uniform weight pointer).
// Lane holds full weight column w[64] in regs; h tile (8KB) in LDS read as
// wave-uniform broadcasts. 4 partial accumulator chains for ILP.
// ---------------------------------------------------------------------------
__global__ __launch_bounds__(256) void k_qkvs(const float* __restrict__ h,
                                              const float* __restrict__ Wq, const float* __restrict__ bq,
                                              const float* __restrict__ Wk, const float* __restrict__ bk,
                                              const float* __restrict__ Wv, const float* __restrict__ bv,
                                              const float* __restrict__ Ws, const float* __restrict__ bs,
                                              float* __restrict__ qkvs) {
    __shared__ float hs[32][64];
    const int t = threadIdx.x;
    const int lane = t & 63;
    const int m = t >> 6;
    const int base = blockIdx.x * 32;

    {   // stage h tile: 512 float4, 2 per thread
        const float4* h4 = (const float4*)h;
#pragma unroll
        for (int i = 0; i < 2; ++i) {
            const int f = t + i * 256;
            const int row = f >> 4, f4 = f & 15;
            int n = base + row; if (n >= NN) n = NN - 1;
            ((float4*)hs)[row * 16 + f4] = h4[(size_t)n * 16 + f4];
        }
    }
    const float* Wm = (m == 0) ? Wq : (m == 1) ? Wk : (m == 2) ? Wv : Ws;
    const float* bm = (m == 0) ? bq : (m == 1) ? bk : (m == 2) ? bv : bs;
    float w[64];
#pragma unroll
    for (int j = 0; j < 64; ++j) w[j] = Wm[j * 64 + lane];
    const float bias = bm[lane];
    __syncthreads();

    for (int n = 0; n < 32; ++n) {
        const float* hr = &hs[n][0];
        float s0 = 0.f, s1 = 0.f, s2 = 0.f, s3 = 0.f;
#pragma unroll
        for (int j = 0; j < 64; j += 4) {
            s0 += hr[j]     * w[j];
            s1 += hr[j + 1] * w[j + 1];
            s2 += hr[j + 2] * w[j + 2];
            s3 += hr[j + 3] * w[j + 3];
        }
        const int nn = base + n;
        if (nn < NN)
            qkvs[(size_t)nn * 256 + m * 64 + lane] = (s0 + s1) + (s2 + s3) + bias;
    }
}

// ---------------------------------------------------------------------------
// K2: per-edge attention logit + segment max. One wave per edge.
// ---------------------------------------------------------------------------
__global__ __launch_bounds__(256) void k_alpha(const int* __restrict__ ei,
                                               const float* __restrict__ eattr,
                                               const float* __restrict__ We,
                                               const float* __restrict__ qkvs,
                                               float* __restrict__ alpha,
                                               unsigned int* __restrict__ menc) {
    const int wid = (blockIdx.x * 256 + threadIdx.x) >> 6;
    const int lane = threadIdx.x & 63;
    if (wid >= NE) return;
    const int src = ei[wid];
    const int dst = ei[NE + wid];
    const float ea0 = eattr[wid * 2], ea1 = eattr[wid * 2 + 1];
    const float ec = ea0 * We[lane] + ea1 * We[C + lane];
    const float qd = qkvs[(size_t)dst * 256 + lane];
    const float ks = qkvs[(size_t)src * 256 + 64 + lane];
    float p = qd * (ks + ec);
#pragma unroll
    for (int off = 32; off > 0; off >>= 1) p += __shfl_xor(p, off, 64);
    if (lane == 0) {
        const float a = p * 0.125f;  // 1/sqrt(64)
        alpha[wid] = a;
        const unsigned int b = __float_as_uint(a);
        const unsigned int e = (b & 0x80000000u) ? ~b : (b | 0x80000000u);
        atomicMax(&menc[dst], e);
    }
}

// ---------------------------------------------------------------------------
// K3: ex = exp(alpha - m[dst]); den[dst] += ex. One thread per edge.
// ---------------------------------------------------------------------------
__global__ __launch_bounds__(256) void k_exp(const int* __restrict__ ei,
                                             const unsigned int* __restrict__ menc,
                                             float* __restrict__ alpha,
                                             float* __restrict__ den) {
    const int e = blockIdx.x * 256 + threadIdx.x;
    if (e >= NE) return;
    const int dst = ei[NE + e];
    const unsigned int u = menc[dst];
    const unsigned int b = (u & 0x80000000u) ? (u & 0x7FFFFFFFu) : ~u;
    const float m = __uint_as_float(b);
    const float ex = __expf(alpha[e] - m);
    alpha[e] = ex;
    atomicAdd(&den[dst], ex);
}

// ---------------------------------------------------------------------------
// K4: agg[dst] += (v[src] + e) * ex  (unnormalized; /den moved to k_update)
// ---------------------------------------------------------------------------
__global__ __launch_bounds__(256) void k_scatter(const int* __restrict__ ei,
                                                 const float* __restrict__ eattr,
                                                 const float* __restrict__ We,
                                                 const float* __restrict__ qkvs,
                                                 const float* __restrict__ alpha,
                                                 float* __restrict__ agg) {
    const int wid = (blockIdx.x * 256 + threadIdx.x) >> 6;
    const int lane = threadIdx.x & 63;
    if (wid >= NE) return;
    const int src = ei[wid];
    const int dst = ei[NE + wid];
    const float a = alpha[wid];
    const float ea0 = eattr[wid * 2], ea1 = eattr[wid * 2 + 1];
    const float ec = ea0 * We[lane] + ea1 * We[C + lane];
    const float v = qkvs[(size_t)src * 256 + 128 + lane];
    atomicAdd(&agg[(size_t)dst * C + lane], (v + ec) * a);
}

// ---------------------------------------------------------------------------
// K5: h_out = leaky_relu(agg/den + (h@Wskip + bskip))
// ---------------------------------------------------------------------------
__global__ __launch_bounds__(256) void k_update(const float* __restrict__ agg,
                                                const float* __restrict__ den,
                                                const float* __restrict__ qkvs,
                                                float* __restrict__ hout) {
    const int idx = blockIdx.x * 256 + threadIdx.x;
    if (idx >= NN * C) return;
    const int n = idx >> 6, c = idx & 63;
    hout[idx] = leaky(agg[idx] / den[n] + qkvs[(size_t)n * 256 + 192 + c]);
}

extern "C" void kernel_launch(void* const* d_in, const int* in_sizes, int n_in,
                              void* d_out, int out_size, void* d_ws, size_t ws_size,
                              hipStream_t stream) {
    const float* x     = (const float*)d_in[0];
    const int*   ei    = (const int*)d_in[1];
    const float* eattr = (const float*)d_in[2];
    const float* Wf    = (const float*)d_in[3];
    const float* bf    = (const float*)d_in[4];
    const float* Wq    = (const float*)d_in[5];
    const float* bq    = (const float*)d_in[6];
    const float* Wk    = (const float*)d_in[7];
    const float* bk    = (const float*)d_in[8];
    const float* Wv    = (const float*)d_in[9];
    const float* bv    = (const float*)d_in[10];
    const float* We    = (const float*)d_in[11];
    const float* Ws    = (const float*)d_in[12];
    const float* bs    = (const float*)d_in[13];
    float* out = (float*)d_out;

    // workspace layout (menc/den/agg contiguous for single memset)
    char* p = (char*)d_ws;
    float* h     = (float*)p; p += (size_t)NN * C * 4;       // 12.8 MB
    float* qkvs  = (float*)p; p += (size_t)NN * 4 * C * 4;   // 51.2 MB
    float* alpha = (float*)p; p += (size_t)NE * 4;           //  3.2 MB
    unsigned int* menc = (unsigned int*)p; p += (size_t)NN * 4;
    float* den   = (float*)p; p += (size_t)NN * 4;
    float* agg   = (float*)p; p += (size_t)NN * C * 4;       // 12.8 MB
    const size_t zero_bytes = ((size_t)NN + NN + (size_t)NN * C) * 4;

    const int gemm_grid = (NN + 31) / 32;
    k_feat<<<gemm_grid, 256, 0, stream>>>(x, Wf, bf, h);

    for (int layer = 0; layer < 3; ++layer) {
        k_qkvs<<<gemm_grid, 256, 0, stream>>>(
            h, Wq, bq, Wk, bk, Wv, bv, Ws, bs, qkvs);
        hipMemsetAsync(menc, 0, zero_bytes, stream);
        k_alpha<<<NE / 4, 256, 0, stream>>>(ei, eattr, We, qkvs, alpha, menc);
        k_exp<<<NE / 256, 256, 0, stream>>>(ei, menc, alpha, den);
        k_scatter<<<NE / 4, 256, 0, stream>>>(ei, eattr, We, qkvs, alpha, agg);
        float* hout = (layer == 2) ? out : h;
        k_update<<<(NN * C + 255) / 256, 256, 0, stream>>>(agg, den, qkvs, hout);
    }
}

// Round 3
// 723.292 us; speedup vs baseline: 2.9256x; 1.9617x over previous
//
#include <hip/hip_runtime.h>

#define NN 50000
#define NE 800000
#define FIN 256
#define C 64
#define NEG_SLOPE 0.01f

__device__ __forceinline__ float leaky(float v) { return v > 0.f ? v : NEG_SLOPE * v; }

__device__ __forceinline__ float wave_sum(float p) {
#pragma unroll
    for (int off = 1; off < 64; off <<= 1) p += __shfl_xor(p, off, 64);
    return p;  // all lanes hold the sum (butterfly)
}

// ---------------------------------------------------------------------------
// K0: h = leaky_relu(x @ Wf + bf)   x:[N,256] Wf:[256,64]
// ---------------------------------------------------------------------------
__global__ __launch_bounds__(256) void k_feat(const float* __restrict__ x,
                                              const float* __restrict__ Wf,
                                              const float* __restrict__ bf,
                                              float* __restrict__ h) {
    __shared__ float xs[32][32];
    const int t = threadIdx.x;
    const int c = t & 63;
    const int g = t >> 6;
    const int base = blockIdx.x * 32;
    float acc[8];
#pragma unroll
    for (int i = 0; i < 8; ++i) acc[i] = 0.f;

    for (int kc = 0; kc < 8; ++kc) {
        __syncthreads();
        {
            const int row = t >> 3, f4 = t & 7;
            int n = base + row; if (n >= NN) n = NN - 1;
            *(float4*)&xs[row][f4 * 4] =
                *(const float4*)(x + (size_t)n * FIN + kc * 32 + f4 * 4);
        }
        __syncthreads();
        float w[32];
#pragma unroll
        for (int j = 0; j < 32; ++j) w[j] = Wf[(kc * 32 + j) * C + c];
#pragma unroll
        for (int i = 0; i < 8; ++i) {
            const float* xr = &xs[g * 8 + i][0];
#pragma unroll
            for (int j = 0; j < 32; ++j) acc[i] += xr[j] * w[j];
        }
    }
    const float bias = bf[c];
#pragma unroll
    for (int i = 0; i < 8; ++i) {
        const int n = base + g * 8 + i;
        if (n < NN) h[(size_t)n * C + c] = leaky(acc[i] + bias);
    }
}

// ---------------------------------------------------------------------------
// K1: qkvs[n, m*64+c] = h[n,:] @ W_m + b_m   for m in {q,k,v,skip}
// ---------------------------------------------------------------------------
__global__ __launch_bounds__(256) void k_qkvs(const float* __restrict__ h,
                                              const float* __restrict__ Wq, const float* __restrict__ bq,
                                              const float* __restrict__ Wk, const float* __restrict__ bk,
                                              const float* __restrict__ Wv, const float* __restrict__ bv,
                                              const float* __restrict__ Ws, const float* __restrict__ bs,
                                              float* __restrict__ qkvs) {
    __shared__ float hs[32][64];
    const int t = threadIdx.x;
    const int lane = t & 63;
    const int m = t >> 6;
    const int base = blockIdx.x * 32;
    {
        const float4* h4 = (const float4*)h;
#pragma unroll
        for (int i = 0; i < 2; ++i) {
            const int f = t + i * 256;
            const int row = f >> 4, f4 = f & 15;
            int n = base + row; if (n >= NN) n = NN - 1;
            ((float4*)hs)[row * 16 + f4] = h4[(size_t)n * 16 + f4];
        }
    }
    const float* Wm = (m == 0) ? Wq : (m == 1) ? Wk : (m == 2) ? Wv : Ws;
    const float* bm = (m == 0) ? bq : (m == 1) ? bk : (m == 2) ? bv : bs;
    float w[64];
#pragma unroll
    for (int j = 0; j < 64; ++j) w[j] = Wm[j * 64 + lane];
    const float bias = bm[lane];
    __syncthreads();

    for (int n = 0; n < 32; ++n) {
        const float* hr = &hs[n][0];
        float s0 = 0.f, s1 = 0.f, s2 = 0.f, s3 = 0.f;
#pragma unroll
        for (int j = 0; j < 64; j += 4) {
            s0 += hr[j]     * w[j];
            s1 += hr[j + 1] * w[j + 1];
            s2 += hr[j + 2] * w[j + 2];
            s3 += hr[j + 3] * w[j + 3];
        }
        const int nn = base + n;
        if (nn < NN)
            qkvs[(size_t)nn * 256 + m * 64 + lane] = (s0 + s1) + (s2 + s3) + bias;
    }
}

// ---------------------------------------------------------------------------
// CSR build: histogram -> scan -> scatter of edge records (src, ea0, ea1)
// ---------------------------------------------------------------------------
__global__ __launch_bounds__(256) void k_hist(const int* __restrict__ ei,
                                              int* __restrict__ deg) {
    const int e = blockIdx.x * 256 + threadIdx.x;
    if (e >= NE) return;
    atomicAdd(&deg[ei[NE + e]], 1);
}

__global__ __launch_bounds__(1024) void k_scan(const int* __restrict__ deg,
                                               int* __restrict__ row_ptr,
                                               int* __restrict__ cursor) {
    __shared__ int part[1024];
    const int t = threadIdx.x;
    const int beg = t * 49;
    int s = 0;
    for (int j = 0; j < 49; ++j) {
        const int i = beg + j;
        if (i < NN) s += deg[i];
    }
    part[t] = s;
    __syncthreads();
    int run = 0;
    for (int j = 0; j < t; ++j) run += part[j];
    for (int j = 0; j < 49; ++j) {
        const int i = beg + j;
        if (i < NN) { row_ptr[i] = run; cursor[i] = run; run += deg[i]; }
    }
    if (t == 1023) row_ptr[NN] = run;  // == NE
}

__global__ __launch_bounds__(256) void k_csr(const int* __restrict__ ei,
                                             const float* __restrict__ eattr,
                                             int* __restrict__ cursor,
                                             float4* __restrict__ erec) {
    const int e = blockIdx.x * 256 + threadIdx.x;
    if (e >= NE) return;
    const int dst = ei[NE + e];
    const int pos = atomicAdd(&cursor[dst], 1);
    erec[pos] = make_float4(__int_as_float(ei[e]), eattr[e * 2], eattr[e * 2 + 1], 0.f);
}

// ---------------------------------------------------------------------------
// K2: fused conv. One wave per destination node, flash-style online softmax.
// h_out[d] = leaky( (sum_j (v[sj]+e_j)*exp(p_j)) / (sum_j exp(p_j)) + skip[d] )
// No atomics, no intermediate edge arrays.
// ---------------------------------------------------------------------------
__global__ __launch_bounds__(256) void k_conv(const int* __restrict__ row_ptr,
                                              const float4* __restrict__ erec,
                                              const float* __restrict__ We,
                                              const float* __restrict__ qkvs,
                                              float* __restrict__ hout) {
    const int lane = threadIdx.x & 63;
    const int d = blockIdx.x * 4 + (threadIdx.x >> 6);
    if (d >= NN) return;
    const float we0 = We[lane], we1 = We[C + lane];
    const float* qrow = qkvs + (size_t)d * 256;
    const float q = qrow[lane];
    const int i0 = row_ptr[d], i1 = row_ptr[d + 1];

    float m = -INFINITY, l = 0.f, acc = 0.f;
    int i = i0;
    for (; i + 1 < i1; i += 2) {  // pairs for ILP on the serial softmax chain
        const float4 r0 = erec[i], r1 = erec[i + 1];
        const float* kv0 = qkvs + (size_t)__float_as_int(r0.x) * 256;
        const float* kv1 = qkvs + (size_t)__float_as_int(r1.x) * 256;
        const float ec0 = r0.y * we0 + r0.z * we1;
        const float ec1 = r1.y * we0 + r1.z * we1;
        const float k0 = kv0[64 + lane], v0 = kv0[128 + lane];
        const float k1 = kv1[64 + lane], v1 = kv1[128 + lane];
        const float P0 = wave_sum(q * (k0 + ec0)) * 0.125f;
        const float P1 = wave_sum(q * (k1 + ec1)) * 0.125f;
        const float mn = fmaxf(m, fmaxf(P0, P1));
        const float s = __expf(m - mn);
        const float e0 = __expf(P0 - mn), e1 = __expf(P1 - mn);
        l = l * s + e0 + e1;
        acc = acc * s + (v0 + ec0) * e0 + (v1 + ec1) * e1;
        m = mn;
    }
    if (i < i1) {  // tail
        const float4 r0 = erec[i];
        const float* kv0 = qkvs + (size_t)__float_as_int(r0.x) * 256;
        const float ec0 = r0.y * we0 + r0.z * we1;
        const float k0 = kv0[64 + lane], v0 = kv0[128 + lane];
        const float P0 = wave_sum(q * (k0 + ec0)) * 0.125f;
        const float mn = fmaxf(m, P0);
        const float s = __expf(m - mn);
        const float e0 = __expf(P0 - mn);
        l = l * s + e0;
        acc = acc * s + (v0 + ec0) * e0;
    }
    const float res = (l > 0.f) ? acc / l : 0.f;
    hout[(size_t)d * C + lane] = leaky(res + qrow[192 + lane]);
}

extern "C" void kernel_launch(void* const* d_in, const int* in_sizes, int n_in,
                              void* d_out, int out_size, void* d_ws, size_t ws_size,
                              hipStream_t stream) {
    const float* x     = (const float*)d_in[0];
    const int*   ei    = (const int*)d_in[1];
    const float* eattr = (const float*)d_in[2];
    const float* Wf    = (const float*)d_in[3];
    const float* bf    = (const float*)d_in[4];
    const float* Wq    = (const float*)d_in[5];
    const float* bq    = (const float*)d_in[6];
    const float* Wk    = (const float*)d_in[7];
    const float* bk    = (const float*)d_in[8];
    const float* Wv    = (const float*)d_in[9];
    const float* bv    = (const float*)d_in[10];
    const float* We    = (const float*)d_in[11];
    const float* Ws    = (const float*)d_in[12];
    const float* bs    = (const float*)d_in[13];
    float* out = (float*)d_out;

    // workspace layout
    char* p = (char*)d_ws;
    float*  h       = (float*)p;  p += (size_t)NN * C * 4;        // 12.8 MB
    float*  qkvs    = (float*)p;  p += (size_t)NN * 4 * C * 4;    // 51.2 MB
    int*    deg     = (int*)p;    p += (size_t)NN * 4;
    int*    row_ptr = (int*)p;    p += (size_t)(NN + 1) * 4;
    int*    cursor  = (int*)p;    p += (size_t)NN * 4;
    float4* erec    = (float4*)p; p += (size_t)NE * 16;           // 12.8 MB

    // CSR build (per call — inputs are restored before every launch)
    hipMemsetAsync(deg, 0, (size_t)NN * 4, stream);
    k_hist<<<(NE + 255) / 256, 256, 0, stream>>>(ei, deg);
    k_scan<<<1, 1024, 0, stream>>>(deg, row_ptr, cursor);
    k_csr<<<(NE + 255) / 256, 256, 0, stream>>>(ei, eattr, cursor, erec);

    const int gemm_grid = (NN + 31) / 32;
    k_feat<<<gemm_grid, 256, 0, stream>>>(x, Wf, bf, h);

    for (int layer = 0; layer < 3; ++layer) {
        k_qkvs<<<gemm_grid, 256, 0, stream>>>(
            h, Wq, bq, Wk, bk, Wv, bv, Ws, bs, qkvs);
        float* hout = (layer == 2) ? out : h;
        k_conv<<<(NN + 3) / 4, 256, 0, stream>>>(row_ptr, erec, We, qkvs, hout);
    }
}